// Round 1
// 4096.502 us; speedup vs baseline: 1.1607x; 1.1607x over previous
//
#include <hip/hip_runtime.h>

// SolarRNN: B=256, T=4096, F=16, H=64. Two fused GRU layers + online-softmax
// attention + MLP tail in ONE persistent kernel: block b = sequence b.
// 4 waves/block (one per SIMD), K-split-4 with LDS reduction, fp32 throughout.
//
// This version (vs 4754us baseline):
//  - amdgpu_waves_per_eu(1,1): grid==1 block/CU, so let the allocator use the
//    full 256-VGPR budget instead of spilling weight slices (was 124 VGPRs).
//  - Software-pipelined: ONE barrier per timestep (was 2). Iteration t reduces
//    L2(t-1) and L1(t) from buffer p, writes L2(t)+L1(t+1) partials to p^1.
//  - Wi2 input-projection folded: o1@Wi2 = h1@Wi2 + 0.5*x@(Wp@Wi2) + const.
//    (Wp@Wi2 computed once per block.) Removes the sO1 readlane broadcast.
//  - shfl score-reduce for step t-1 issues early, consumed after the partials
//    FMA block (overlapped instead of serial tail).

#define B_ 256
#define T_ 4096
#define F_ 16
#define H_ 64
#define L2E 1.4426950408889634f

__device__ __forceinline__ float rdlane(float v, int lane) {
    return __builtin_bit_cast(float, __builtin_amdgcn_readlane(__builtin_bit_cast(int, v), lane));
}
__device__ __forceinline__ float sigm(float x) {
    float e = __builtin_amdgcn_exp2f(-L2E * x);
    return __builtin_amdgcn_rcpf(1.0f + e);
}
__device__ __forceinline__ float tanh_(float x) {
    float e = __builtin_amdgcn_exp2f(2.0f * L2E * x);
    return 1.0f - 2.0f * __builtin_amdgcn_rcpf(1.0f + e);
}

__launch_bounds__(256)
__attribute__((amdgpu_waves_per_eu(1, 1)))
__global__ void solar_rnn(const float* __restrict__ x,
                          const float* __restrict__ Wi1, const float* __restrict__ bi1,
                          const float* __restrict__ Whr1, const float* __restrict__ Whz1,
                          const float* __restrict__ Whn1, const float* __restrict__ bhn1,
                          const float* __restrict__ Wi2, const float* __restrict__ bi2,
                          const float* __restrict__ Whr2, const float* __restrict__ Whz2,
                          const float* __restrict__ Whn2, const float* __restrict__ bhn2,
                          const float* __restrict__ Wp, const float* __restrict__ bp,
                          const float* __restrict__ Wa,
                          const float* __restrict__ W1, const float* __restrict__ b1,
                          const float* __restrict__ W2, const float* __restrict__ b2,
                          const float* __restrict__ W3, const float* __restrict__ b3,
                          const float* __restrict__ W4, const float* __restrict__ b4,
                          float* __restrict__ out)
{
    const int b   = blockIdx.x;
    const int tid = threadIdx.x;
    const int w   = tid >> 6;   // wave 0..3 (one per SIMD)
    const int j   = tid & 63;   // lane = output index
    const int wj  = (w << 6) + j;

    // double-buffered partials: [buf][acc][wave][j]; slots 0..4 = L1 (r,z,in,hn,xp),
    // slots 5..8 = L2 (r,z,in,hn). Lane j stride-1 -> conflict-free.
    __shared__ float red[2][9][4][H_];
    __shared__ float sm_a[128];
    __shared__ float sm_b[128];

    // ---- per-lane weight slices (wave w owns K-rows [16w,16w+16)) ----
    float wr1[16], wz1[16], wn1[16];        // layer-1 hidden kernels, col j
    float wr2[16], wz2[16], wn2[16];        // layer-2 hidden kernels, col j
    float u2r[16], u2z[16], u2n[16];        // Wi2 (h1 -> gates), col j
    #pragma unroll
    for (int k = 0; k < 16; ++k) {
        const int row = 16 * w + k;
        wr1[k] = Whr1[row * H_ + j];
        wz1[k] = Whz1[row * H_ + j];
        wn1[k] = Whn1[row * H_ + j];
        wr2[k] = Whr2[row * H_ + j];
        wz2[k] = Whz2[row * H_ + j];
        wn2[k] = Whn2[row * H_ + j];
        u2r[k] = Wi2[row * 192 + j];
        u2z[k] = Wi2[row * 192 + 64 + j];
        u2n[k] = Wi2[row * 192 + 128 + j];
    }
    float w1r[4], w1z[4], w1n[4], wpv[4];   // Wi1 / Wp (K=16 -> 4 rows per wave)
    float x2r[4], x2z[4], x2n[4];           // 0.5 * (Wp @ Wi2) rows, col j
    #pragma unroll
    for (int kk = 0; kk < 4; ++kk) {
        const int row = 4 * w + kk;
        w1r[kk] = Wi1[row * 192 + j];
        w1z[kk] = Wi1[row * 192 + 64 + j];
        w1n[kk] = Wi1[row * 192 + 128 + j];
        wpv[kk] = Wp[row * H_ + j];
        float ar = 0.f, az = 0.f, an = 0.f;
        for (int m = 0; m < H_; ++m) {
            const float wp = Wp[row * H_ + m];          // uniform (broadcast) load
            ar = fmaf(wp, Wi2[m * 192 + j],       ar);  // coalesced over j
            az = fmaf(wp, Wi2[m * 192 + 64 + j],  az);
            an = fmaf(wp, Wi2[m * 192 + 128 + j], an);
        }
        x2r[kk] = 0.5f * ar; x2z[kk] = 0.5f * az; x2n[kk] = 0.5f * an;
    }
    // fold bp @ Wi2 into the L2 gate biases (bp==0 in this problem, but exact)
    float cbr = 0.f, cbz = 0.f, cbn = 0.f;
    for (int m = 0; m < H_; ++m) {
        const float bpm = bp[m];
        cbr = fmaf(bpm, Wi2[m * 192 + j],       cbr);
        cbz = fmaf(bpm, Wi2[m * 192 + 64 + j],  cbz);
        cbn = fmaf(bpm, Wi2[m * 192 + 128 + j], cbn);
    }
    const float bi1r = bi1[j], bi1z = bi1[64 + j], bi1n = bi1[128 + j], bh1 = bhn1[j];
    const float bb2r = bi2[j]       + 0.5f * cbr;
    const float bb2z = bi2[64 + j]  + 0.5f * cbz;
    const float bb2n = bi2[128 + j] + 0.5f * cbn;
    const float bh2  = bhn2[j];
    const float bpj  = bp[j], waj = Wa[j];
    // ba is a constant shift on pre-softmax scores -> softmax-invariant, skipped.

    float h1 = 0.f, h2 = 0.f, o1 = 0.f;     // lane j holds state[j], replicated per wave
    float am = -3.0e38f, al = 0.f, aa = 0.f;
    float sH1[16], sH2[16];                 // wave-uniform h-slices (readlane -> SGPR)
    #pragma unroll
    for (int k = 0; k < 16; ++k) { sH1[k] = 0.f; sH2[k] = 0.f; }

    const float* xb = x + (size_t)b * T_ * F_;
    // chunked x: lane l holds x[c*64+l][4w..4w+4); prefetch one chunk (64 steps) ahead
    float4 xq_cur  = *(const float4*)(xb + ((size_t)j * F_ + 4 * w));
    float4 xq_next = *(const float4*)(xb + ((size_t)(64 + j) * F_ + 4 * w));

    float* pr_ = &red[0][0][0][0];
    float* pw_ = &red[1][0][0][0];

    // partials for L2(t) (from sH2=h2(t-1), sH1=h1(t), xs=x(t)) and
    // L1(t+1) (from sH1=h1(t), xn=x(t+1)), written to buffer d.
    auto do_partials = [&](float xs0, float xs1, float xs2, float xs3,
                           float xn0, float xn1, float xn2, float xn3,
                           float* __restrict__ d) {
        float ar2 = fmaf(xs0, x2r[0], fmaf(xs1, x2r[1], fmaf(xs2, x2r[2], xs3 * x2r[3])));
        float az2 = fmaf(xs0, x2z[0], fmaf(xs1, x2z[1], fmaf(xs2, x2z[2], xs3 * x2z[3])));
        float an2 = fmaf(xs0, x2n[0], fmaf(xs1, x2n[1], fmaf(xs2, x2n[2], xs3 * x2n[3])));
        float hn2 = 0.f;
        #pragma unroll
        for (int k = 0; k < 16; ++k) {
            ar2 = fmaf(sH2[k], wr2[k], ar2);
            az2 = fmaf(sH2[k], wz2[k], az2);
            hn2 = fmaf(sH2[k], wn2[k], hn2);
        }
        #pragma unroll
        for (int k = 0; k < 16; ++k) {
            ar2 = fmaf(sH1[k], u2r[k], ar2);
            az2 = fmaf(sH1[k], u2z[k], az2);
            an2 = fmaf(sH1[k], u2n[k], an2);
        }
        d[5 * 256 + wj] = ar2;
        d[6 * 256 + wj] = az2;
        d[7 * 256 + wj] = an2;
        d[8 * 256 + wj] = hn2;

        float ar1 = fmaf(xn0, w1r[0], fmaf(xn1, w1r[1], fmaf(xn2, w1r[2], xn3 * w1r[3])));
        float az1 = fmaf(xn0, w1z[0], fmaf(xn1, w1z[1], fmaf(xn2, w1z[2], xn3 * w1z[3])));
        float an1 = fmaf(xn0, w1n[0], fmaf(xn1, w1n[1], fmaf(xn2, w1n[2], xn3 * w1n[3])));
        float axp = fmaf(xn0, wpv[0], fmaf(xn1, wpv[1], fmaf(xn2, wpv[2], xn3 * wpv[3])));
        float hn1 = 0.f;
        #pragma unroll
        for (int k = 0; k < 16; ++k) {
            ar1 = fmaf(sH1[k], wr1[k], ar1);
            az1 = fmaf(sH1[k], wz1[k], az1);
            hn1 = fmaf(sH1[k], wn1[k], hn1);
        }
        d[0 * 256 + wj] = ar1;
        d[1 * 256 + wj] = az1;
        d[2 * 256 + wj] = an1;
        d[3 * 256 + wj] = hn1;
        d[4 * 256 + wj] = axp;
    };

    #define RD(a) ((pr_[(a) * 256 + j] + pr_[(a) * 256 + 64 + j]) + \
                   (pr_[(a) * 256 + 128 + j] + pr_[(a) * 256 + 192 + j]))

    float cx0, cx1, cx2, cx3;   // x(t) scalars carried across iterations (uniform)

    // ---- prologue: step 0 (h1=h2=0) ----
    {
        const float xs0 = rdlane(xq_cur.x, 0), xs1 = rdlane(xq_cur.y, 0),
                    xs2 = rdlane(xq_cur.z, 0), xs3 = rdlane(xq_cur.w, 0);
        float ar1 = fmaf(xs0, w1r[0], fmaf(xs1, w1r[1], fmaf(xs2, w1r[2], xs3 * w1r[3])));
        float az1 = fmaf(xs0, w1z[0], fmaf(xs1, w1z[1], fmaf(xs2, w1z[2], xs3 * w1z[3])));
        float an1 = fmaf(xs0, w1n[0], fmaf(xs1, w1n[1], fmaf(xs2, w1n[2], xs3 * w1n[3])));
        float axp = fmaf(xs0, wpv[0], fmaf(xs1, wpv[1], fmaf(xs2, wpv[2], xs3 * wpv[3])));
        pr_[0 * 256 + wj] = ar1;
        pr_[1 * 256 + wj] = az1;
        pr_[2 * 256 + wj] = an1;
        pr_[3 * 256 + wj] = 0.f;
        pr_[4 * 256 + wj] = axp;
        __syncthreads();
        const float p1r = RD(0), p1z = RD(1), p1n = RD(2), p1h = RD(3), p1x = RD(4);
        const float r1 = sigm(p1r + bi1r);
        const float z1 = sigm(p1z + bi1z);
        const float n1 = tanh_((p1n + bi1n) + r1 * (p1h + bh1));
        h1 = n1 + z1 * (h1 - n1);
        o1 = h1 + 0.5f * (p1x + bpj);
        #pragma unroll
        for (int k = 0; k < 16; ++k) sH1[k] = rdlane(h1, 16 * w + k);
        const float xn0 = rdlane(xq_cur.x, 1), xn1 = rdlane(xq_cur.y, 1),
                    xn2 = rdlane(xq_cur.z, 1), xn3 = rdlane(xq_cur.w, 1);
        do_partials(xs0, xs1, xs2, xs3, xn0, xn1, xn2, xn3, pw_);   // sH2 = 0
        cx0 = xn0; cx1 = xn1; cx2 = xn2; cx3 = xn3;
        float* tp = pr_; pr_ = pw_; pw_ = tp;
        __syncthreads();
    }

    // ---- main pipelined loop: iteration t reduces L2(t-1) and L1(t),
    //      writes L2(t) + L1(t+1) partials, ONE barrier per step ----
    #pragma unroll 1
    for (int t = 1; t < T_; ++t) {
        const int u = t + 1;                 // x index needed for L1(t+1)
        if ((u & 63) == 0) {                 // chunk rotation, once per 64 steps
            xq_cur = xq_next;
            const int c = (u >> 6) + 1;
            if (c < T_ / 64)
                xq_next = *(const float4*)(xb + ((size_t)(c * 64 + j) * F_ + 4 * w));
        }
        const int ul = u & 63;
        const float xn0 = rdlane(xq_cur.x, ul), xn1 = rdlane(xq_cur.y, ul),
                    xn2 = rdlane(xq_cur.z, ul), xn3 = rdlane(xq_cur.w, ul);

        // all cross-wave partial reads issued up front (one LDS latency)
        const float qr  = RD(5), qz  = RD(6), qin = RD(7), qhn = RD(8);
        const float p1r = RD(0), p1z = RD(1), p1n = RD(2), p1h = RD(3), p1x = RD(4);

        // L2(t-1) pointwise
        const float r2 = sigm(qr + bb2r);
        const float z2 = sigm(qz + bb2z);
        const float n2 = tanh_((qin + bb2n) + r2 * (qhn + bh2));
        h2 = n2 + z2 * (h2 - n2);
        const float o2 = h2 + 0.5f * o1;     // o1 still holds o1(t-1)
        // score reduce for s(t-1): issue early, consume after partials
        float p = o2 * waj;
        #pragma unroll
        for (int mask = 32; mask >= 1; mask >>= 1) p += __shfl_xor(p, mask);
        #pragma unroll
        for (int k = 0; k < 16; ++k) sH2[k] = rdlane(h2, 16 * w + k);

        // L1(t) pointwise
        const float r1 = sigm(p1r + bi1r);
        const float z1 = sigm(p1z + bi1z);
        const float n1 = tanh_((p1n + bi1n) + r1 * (p1h + bh1));
        h1 = n1 + z1 * (h1 - n1);
        o1 = h1 + 0.5f * (p1x + bpj);
        #pragma unroll
        for (int k = 0; k < 16; ++k) sH1[k] = rdlane(h1, 16 * w + k);

        do_partials(cx0, cx1, cx2, cx3, xn0, xn1, xn2, xn3, pw_);

        // online-softmax update with s(t-1)
        const float mn = fmaxf(am, p);
        const float ca = __builtin_amdgcn_exp2f((am - mn) * L2E);
        const float ce = __builtin_amdgcn_exp2f((p  - mn) * L2E);
        al = fmaf(al, ca, ce);
        aa = fmaf(aa, ca, ce * o2);
        am = mn;

        cx0 = xn0; cx1 = xn1; cx2 = xn2; cx3 = xn3;
        float* tp = pr_; pr_ = pw_; pw_ = tp;
        __syncthreads();
    }

    // ---- epilogue: finish L2(T-1) + its softmax contribution ----
    {
        const float qr = RD(5), qz = RD(6), qin = RD(7), qhn = RD(8);
        const float r2 = sigm(qr + bb2r);
        const float z2 = sigm(qz + bb2z);
        const float n2 = tanh_((qin + bb2n) + r2 * (qhn + bh2));
        h2 = n2 + z2 * (h2 - n2);
        const float o2 = h2 + 0.5f * o1;
        float p = o2 * waj;
        #pragma unroll
        for (int mask = 32; mask >= 1; mask >>= 1) p += __shfl_xor(p, mask);
        const float mn = fmaxf(am, p);
        const float ca = __builtin_amdgcn_exp2f((am - mn) * L2E);
        const float ce = __builtin_amdgcn_exp2f((p  - mn) * L2E);
        al = fmaf(al, ca, ce);
        aa = fmaf(aa, ca, ce * o2);
    }
    #undef RD

    // ---- attended vector + MLP tail (once per block) ----
    const float att = aa / al;
    if (tid < 64) sm_a[tid] = att;          // wave-0 copy (replicated across waves)
    __syncthreads();

    float v1 = 0.f;
    if (tid < 128) {
        float a = b1[tid];
        for (int k = 0; k < 64; ++k) a = fmaf(sm_a[k], W1[k * 128 + tid], a);
        v1 = fmaxf(a, 0.f);
    }
    __syncthreads();
    if (tid < 128) sm_b[tid] = v1;
    __syncthreads();
    if (tid < 64) {
        float a = b2[tid];
        for (int k = 0; k < 128; ++k) a = fmaf(sm_b[k], W2[k * 64 + tid], a);
        sm_a[tid] = fmaxf(a, 0.f);
    }
    __syncthreads();
    if (tid < 32) {
        float a = b3[tid];
        for (int k = 0; k < 64; ++k) a = fmaf(sm_a[k], W3[k * 32 + tid], a);
        sm_b[tid] = fmaxf(a, 0.f);
    }
    __syncthreads();
    if (tid < 2) {
        float a = b4[tid];
        for (int k = 0; k < 32; ++k) a = fmaf(sm_b[k], W4[k * 2 + tid], a);
        out[b * 2 + tid] = a;
    }
}

extern "C" void kernel_launch(void* const* d_in, const int* in_sizes, int n_in,
                              void* d_out, int out_size, void* d_ws, size_t ws_size,
                              hipStream_t stream) {
    const float* x    = (const float*)d_in[0];
    const float* Wi1  = (const float*)d_in[1];
    const float* bi1  = (const float*)d_in[2];
    const float* Whr1 = (const float*)d_in[3];
    const float* Whz1 = (const float*)d_in[4];
    const float* Whn1 = (const float*)d_in[5];
    const float* bhn1 = (const float*)d_in[6];
    const float* Wi2  = (const float*)d_in[7];
    const float* bi2  = (const float*)d_in[8];
    const float* Whr2 = (const float*)d_in[9];
    const float* Whz2 = (const float*)d_in[10];
    const float* Whn2 = (const float*)d_in[11];
    const float* bhn2 = (const float*)d_in[12];
    const float* Wp   = (const float*)d_in[13];
    const float* bp   = (const float*)d_in[14];
    const float* Wa   = (const float*)d_in[15];
    // d_in[16] = ba: softmax shift-invariant, unused
    const float* W1   = (const float*)d_in[17];
    const float* b1   = (const float*)d_in[18];
    const float* W2   = (const float*)d_in[19];
    const float* b2   = (const float*)d_in[20];
    const float* W3   = (const float*)d_in[21];
    const float* b3   = (const float*)d_in[22];
    const float* W4   = (const float*)d_in[23];
    const float* b4   = (const float*)d_in[24];

    solar_rnn<<<dim3(B_), dim3(256), 0, stream>>>(
        x, Wi1, bi1, Whr1, Whz1, Whn1, bhn1,
        Wi2, bi2, Whr2, Whz2, Whn2, bhn2,
        Wp, bp, Wa, W1, b1, W2, b2, W3, b3, W4, b4,
        (float*)d_out);
}